// Round 6
// baseline (785.340 us; speedup 1.0000x reference)
//
#include <hip/hip_runtime.h>
#include <cstdint>
#include <cstddef>

#define NN 50000
#define EE 600000
#define DD 128
#define NSEG (NN*2)
#define NPART ((NSEG + 255) / 256)   // 391

typedef short bf16x8 __attribute__((ext_vector_type(8)));
typedef float f32x4 __attribute__((ext_vector_type(4)));

// async global->LDS DMA, 16B per lane; LDS dest is wave-uniform base + lane*16
#define GLDS16(gp, lp) __builtin_amdgcn_global_load_lds( \
    (const __attribute__((address_space(1))) void*)(gp), \
    (__attribute__((address_space(3))) void*)(lp), 16, 0, 0)

__device__ __forceinline__ float leaky_f(float x){ return x > 0.f ? x : 0.01f*x; }

__device__ __forceinline__ unsigned short f2bf(float f){
    unsigned u = __float_as_uint(f);
    u += 0x7fffu + ((u >> 16) & 1u);       // round-to-nearest-even
    return (unsigned short)(u >> 16);
}

// truncation hi/lo split: hi=trunc_bf16(a), lo=trunc_bf16(a-hi). err <= 2^-17 |a|
__device__ __forceinline__ void split8(const float* a, bf16x8& hi, bf16x8& lo){
#pragma unroll
    for (int j=0;j<8;j++){
        unsigned u  = __float_as_uint(a[j]);
        unsigned uh = u & 0xFFFF0000u;
        hi[j] = (short)(uh >> 16);
        float lf = a[j] - __uint_as_float(uh);
        lo[j] = (short)(__float_as_uint(lf) >> 16);
    }
}

// =============== weight pre-pack kernels ====================================
// Fragment order: for matrix, kb(768 only), ks, c, lane(=q*16+n16), j:
//   value = bf16( W[ k = kb*128 + ks*32 + q*8 + j ][ n = c*16 + n16 ] )
// so a wave's bf16x8 fragment load is a dense, lane-linear 1KB read.
// Packed images overlay the dead `deg` array (CSR scratch): footprint identical
// to the known-good baseline layout.

// Wd (768x32) -> images [6 kb][4 ks][2 c][64 lane][8 j]; Wt likewise. 24576 shorts each.
__global__ __launch_bounds__(256) void pack768_k(
    const float* __restrict__ Wd, const float* __restrict__ Wt,
    unsigned short* __restrict__ out)
{
    int idx = blockIdx.x*256 + threadIdx.x;       // 49152 total (= 192 blocks)
    int m = idx / 24576;
    int r = idx - m*24576;
    int kb   = r >> 12;
    int ks   = (r >> 10) & 3;
    int c    = (r >> 9) & 1;
    int lane = (r >> 3) & 63;
    int j    = r & 7;
    int q = lane >> 4, n16 = lane & 15;
    int k = kb*128 + ks*32 + q*8 + j;
    int n = c*16 + n16;
    const float* W = m ? Wt : Wd;
    out[idx] = f2bf(W[k*32 + n]);
}

// 8 matrices of 128x128 -> [4 ks][8 c][64 lane][8 j] = 16384 shorts per matrix.
__global__ __launch_bounds__(256) void pack128_k(
    const float* __restrict__ W0, const float* __restrict__ W1,
    const float* __restrict__ W2, const float* __restrict__ W3,
    const float* __restrict__ W4, const float* __restrict__ W5,
    const float* __restrict__ W6, const float* __restrict__ W7,
    unsigned short* __restrict__ out)
{
    int idx = blockIdx.x*256 + threadIdx.x;       // 131072 total (= 512 blocks)
    int m = idx >> 14;
    int r = idx & 16383;
    int ks   = r >> 12;
    int c    = (r >> 9) & 7;
    int lane = (r >> 3) & 63;
    int j    = r & 7;
    int q = lane >> 4, n16 = lane & 15;
    int k = ks*32 + q*8 + j;
    int n = c*16 + n16;
    const float* Ws[8] = {W0,W1,W2,W3,W4,W5,W6,W7};
    out[idx] = f2bf(Ws[m][k*128 + n]);
}

// ============ dual projection kernel: K=768, DMA-staged A, no reg pipeline ===
// per block: 64 rows x 32 cols. A tile (64x128 f32 = 32KB) double-buffered in
// LDS via global_load_lds: each thread DMAs exactly the fragments it will
// consume; LDS layout [wv][ks][half][lane*16] -> stride-16 conflict-free reads.
// B fragments read directly from packed L2-resident image.
__global__ __launch_bounds__(256) void proj_k(
    const float* __restrict__ A0, const float* __restrict__ A1,
    const unsigned short* __restrict__ Bp,
    const float* __restrict__ bias0, const float* __restrict__ bias1,
    float* __restrict__ C, int M)
{
    constexpr int K = 768, CT = 2;
    __shared__ unsigned char sm[2][32768];
    const int tid = threadIdx.x;
    const int lane = tid & 63;
    const int wv = tid >> 6;
    const int q = lane >> 4, n16 = lane & 15;
    const int bm = blockIdx.x * 64;
    const int arow = bm + wv*16 + n16;
    const float* A = blockIdx.y ? A1 : A0;
    const unsigned short* bp = Bp + (size_t)blockIdx.y * 24576 + lane*8;
    const float* bias = blockIdx.y ? bias1 : bias0;
    const int c0 = blockIdx.y * 32;
    const bool rowok = arow < M;
    const float* arowp = A + (size_t)(rowok ? arow : 0) * K;   // clamped: OOB rows load row 0, outputs discarded

    f32x4 acc[CT];
#pragma unroll
    for (int c=0;c<CT;c++) acc[c] = (f32x4){0.f,0.f,0.f,0.f};

#define PSTAGE(BUF, KB) { \
    _Pragma("unroll") \
    for (int ks=0; ks<4; ks++){ \
        _Pragma("unroll") \
        for (int hf=0; hf<2; hf++){ \
            const float* gp = arowp + (KB)*128 + ks*32 + q*8 + hf*4; \
            GLDS16(gp, sm[BUF] + wv*8192 + ks*2048 + hf*1024); \
        } \
    } }

#define PCOMP(BUF, KB) { \
    bf16x8 br[8]; \
    _Pragma("unroll") \
    for (int f=0; f<8; f++) \
        br[f] = *reinterpret_cast<const bf16x8*>(bp + (size_t)((KB)*8 + f)*512); \
    _Pragma("unroll") \
    for (int ks=0; ks<4; ks++){ \
        const unsigned char* ab = sm[BUF] + wv*8192 + ks*2048 + lane*16; \
        float4 t0 = *reinterpret_cast<const float4*>(ab); \
        float4 t1 = *reinterpret_cast<const float4*>(ab + 1024); \
        float a[8]; \
        a[0]=t0.x;a[1]=t0.y;a[2]=t0.z;a[3]=t0.w; \
        a[4]=t1.x;a[5]=t1.y;a[6]=t1.z;a[7]=t1.w; \
        bf16x8 ah, al; split8(a, ah, al); \
        _Pragma("unroll") \
        for (int c=0;c<CT;c++){ \
            acc[c] = __builtin_amdgcn_mfma_f32_16x16x32_bf16(ah, br[ks*2+c], acc[c], 0,0,0); \
            acc[c] = __builtin_amdgcn_mfma_f32_16x16x32_bf16(al, br[ks*2+c], acc[c], 0,0,0); \
        } \
    } }

    PSTAGE(0, 0)
#pragma unroll
    for (int kb=0; kb<6; kb++){
        __syncthreads();                      // drains staging of cur (compiler vmcnt(0))
        if (kb < 5) { PSTAGE(((kb+1)&1), (kb+1)) }   // DMA next tile, overlaps compute
        PCOMP((kb&1), kb)
    }

    const int orow = bm + wv*16 + q*4;
#pragma unroll
    for (int c=0;c<CT;c++) {
        float bb = bias[c*16 + n16];
#pragma unroll
        for (int i=0;i<4;i++) {
            int r = orow + i;
            if (r < M) C[(size_t)r*DD + c0 + c*16 + n16] = leaky_f(acc[c][i] + bb);
        }
    }
#undef PSTAGE
#undef PCOMP
}

// ============ K=128 MFMA GEMM, all A tiles DMA-staged up front ==============
// S stages: C = sum_s A_s @ B_s (+bias). BFMASK bit s => A_s is bf16 (else f32,
// split hi/lo). All A tiles staged via global_load_lds with ONE barrier, then
// the whole compute runs from LDS (conflict-free lane-linear layout) + L2 B.
template<int S,int BFMASK,int LEAKY,int HEAD,int LNRED,int BI0,int BI1,int BI2>
__global__ __launch_bounds__(256) void mfgemm_k(
    const void* __restrict__ A0, const void* __restrict__ A1, const void* __restrict__ A2,
    const unsigned short* __restrict__ Bp,
    const float* __restrict__ bias, float* __restrict__ C, int M,
    const float* __restrict__ W3, const float* __restrict__ b3,
    float* __restrict__ red, float* __restrict__ outv)
{
    constexpr int CT = 8;
    constexpr int sz0 = ((BFMASK>>0)&1) ? 16384 : 32768;
    constexpr int sz1 = (S>1) ? ((((BFMASK)>>1)&1) ? 16384 : 32768) : 0;
    constexpr int sz2 = (S>2) ? ((((BFMASK)>>2)&1) ? 16384 : 32768) : 0;
    __shared__ unsigned char sm[sz0+sz1+sz2];
    const int sbase[3] = {0, sz0, sz0+sz1};

    const int tid = threadIdx.x;
    const int lane = tid & 63;
    const int wv = tid >> 6;
    const int q = lane >> 4, n16 = lane & 15;
    const int bm = blockIdx.x * 64;
    const int arow = bm + wv*16 + n16;
    const bool rowok = arow < M;
    const int arowc = rowok ? arow : 0;    // clamped: OOB rows load row 0, outputs discarded

    f32x4 acc[CT];
#pragma unroll
    for (int c=0;c<CT;c++) acc[c] = (f32x4){0.f,0.f,0.f,0.f};

    const void* As[3] = {A0, A1, A2};
    constexpr int BI[3] = {BI0, BI1, BI2};
    const unsigned short* bpl = Bp + lane*8;

    // ---- stage ALL A tiles (async DMA), single barrier
#pragma unroll
    for (int s=0; s<S; s++){
        if (!((BFMASK >> s) & 1)) {   // f32 tile: 32KB, [wv][ks][hf][lane*16]
#pragma unroll
            for (int ks=0; ks<4; ks++){
#pragma unroll
                for (int hf=0; hf<2; hf++){
                    const float* gp = (const float*)As[s] + (size_t)arowc*DD + ks*32 + q*8 + hf*4;
                    GLDS16(gp, sm + sbase[s] + wv*8192 + ks*2048 + hf*1024);
                }
            }
        } else {                      // bf16 tile: 16KB, [wv][ks][lane*16]
#pragma unroll
            for (int ks=0; ks<4; ks++){
                const unsigned short* gp = (const unsigned short*)As[s] + (size_t)arowc*DD + ks*32 + q*8;
                GLDS16(gp, sm + sbase[s] + wv*4096 + ks*1024);
            }
        }
    }
    __syncthreads();

    // ---- compute, fully from LDS + L2-resident packed B
#pragma unroll
    for (int t=0; t<S*4; t++){
        const int SS = t>>2, KS = t&3;
        bf16x8 br[8];
        const unsigned short* bpp = bpl + BI[SS]*16384 + KS*4096;
#pragma unroll
        for (int c=0;c<8;c++) br[c] = *reinterpret_cast<const bf16x8*>(bpp + c*512);
        if (!((BFMASK >> SS) & 1)) {
            const unsigned char* ab = sm + sbase[SS] + wv*8192 + KS*2048 + lane*16;
            float4 t0 = *reinterpret_cast<const float4*>(ab);
            float4 t1 = *reinterpret_cast<const float4*>(ab + 1024);
            float a[8];
            a[0]=t0.x;a[1]=t0.y;a[2]=t0.z;a[3]=t0.w;
            a[4]=t1.x;a[5]=t1.y;a[6]=t1.z;a[7]=t1.w;
            bf16x8 ah, al; split8(a, ah, al);
#pragma unroll
            for (int c=0;c<CT;c++){
                acc[c] = __builtin_amdgcn_mfma_f32_16x16x32_bf16(ah, br[c], acc[c], 0,0,0);
                acc[c] = __builtin_amdgcn_mfma_f32_16x16x32_bf16(al, br[c], acc[c], 0,0,0);
            }
        } else {
            bf16x8 arb = *reinterpret_cast<const bf16x8*>(sm + sbase[SS] + wv*4096 + KS*1024 + lane*16);
#pragma unroll
            for (int c=0;c<CT;c++)
                acc[c] = __builtin_amdgcn_mfma_f32_16x16x32_bf16(arb, br[c], acc[c], 0,0,0);
        }
    }

    // ---- epilogue
    const int orow = bm + wv*16 + q*4;
    if (HEAD) {
        float w3c[CT];
#pragma unroll
        for (int c=0;c<CT;c++) w3c[c] = W3[c*16 + n16];
        float bb3 = b3[0];
#pragma unroll
        for (int i=0;i<4;i++) {
            float t = 0.f;
#pragma unroll
            for (int c=0;c<CT;c++) {
                float v = acc[c][i] + bias[c*16 + n16];
                if (LEAKY) v = leaky_f(v);
                t = fmaf(v, w3c[c], t);
            }
#pragma unroll
            for (int m=1;m<16;m<<=1) t += __shfl_xor(t, m);
            int r = orow + i;
            if (n16 == 0 && r < M) outv[r] = 1.f / (1.f + expf(-(t + bb3)));
        }
    } else {
        float s = 0.f, ss = 0.f;
#pragma unroll
        for (int c=0;c<CT;c++) {
            float bb = bias[c*16 + n16];
#pragma unroll
            for (int i=0;i<4;i++) {
                int r = orow + i;
                if (r < M) {
                    float v = acc[c][i] + bb;
                    if (LEAKY) v = leaky_f(v);
                    C[(size_t)r*DD + c*16 + n16] = v;
                    if (LNRED) { s += v; ss = fmaf(v, v, ss); }
                }
            }
        }
        if (LNRED) {
#pragma unroll
            for (int o=32;o>0;o>>=1) { s += __shfl_down(s,o); ss += __shfl_down(ss,o); }
            __shared__ float rs[4], rss[4];
            if (lane == 0) { rs[wv] = s; rss[wv] = ss; }
            __syncthreads();
            if (tid == 0) {
                atomicAdd(&red[0], rs[0]+rs[1]+rs[2]+rs[3]);
                atomicAdd(&red[1], rss[0]+rss[1]+rss[2]+rss[3]);
            }
        }
    }
}

// ---------------- small-K projections (num: cols 64..95, cat: cols 96..127) --------
__global__ void numcat_k(const float* __restrict__ numf, const float* __restrict__ catf,
                         const float* __restrict__ Wn, const float* __restrict__ bn,
                         const float* __restrict__ Wc, const float* __restrict__ bc,
                         float* __restrict__ x)
{
    int t = blockIdx.x*blockDim.x + threadIdx.x;
    if (t >= NN*64) return;
    int n = t >> 6, c = t & 63;
    if (c < 32) {
        float acc = bn[c];
#pragma unroll
        for (int k=0;k<5;k++) acc = fmaf(numf[n*5+k], Wn[k*32+c], acc);
        x[(size_t)n*DD + 64 + c] = leaky_f(acc);
    } else {
        int cc = c - 32;
        float acc = bc[cc];
#pragma unroll
        for (int k=0;k<3;k++) acc = fmaf(catf[n*3+k], Wc[k*32+cc], acc);
        x[(size_t)n*DD + 96 + cc] = leaky_f(acc);
    }
}

// ---------------- CSR build ----------------
__global__ void zero_int_k(int* __restrict__ p, int n)
{
    int i = blockIdx.x*blockDim.x + threadIdx.x;
    if (i < n) p[i] = 0;
}

__global__ void hist_k(const int* __restrict__ ei, const int* __restrict__ et,
                       int* __restrict__ deg)
{
    int e = blockIdx.x*blockDim.x + threadIdx.x;
    if (e >= EE) return;
    atomicAdd(&deg[ei[EE + e]*2 + et[e]], 1);
}

__global__ __launch_bounds__(256) void part_reduce_k(const int* __restrict__ deg,
                                                     int* __restrict__ part)
{
    __shared__ int s[256];
    int t = threadIdx.x;
    int i = blockIdx.x*256 + t;
    s[t] = (i < NSEG) ? deg[i] : 0;
    __syncthreads();
#pragma unroll
    for (int o=128;o>0;o>>=1) {
        if (t < o) s[t] += s[t+o];
        __syncthreads();
    }
    if (t == 0) part[blockIdx.x] = s[0];
}

__global__ __launch_bounds__(512) void part_scan_k(int* __restrict__ part)
{
    __shared__ int ps[512];
    int t = threadIdx.x;
    int v = (t < NPART) ? part[t] : 0;
    ps[t] = v; __syncthreads();
    for (int o=1;o<512;o<<=1) {
        int u = (t >= o) ? ps[t-o] : 0;
        __syncthreads();
        ps[t] += u;
        __syncthreads();
    }
    if (t < NPART) part[t] = ps[t] - v;   // exclusive
}

__global__ __launch_bounds__(256) void final_scan_k(const int* __restrict__ deg,
                                                    const int* __restrict__ part,
                                                    int* __restrict__ offs,
                                                    int* __restrict__ cursor)
{
    __shared__ int ps[256];
    int t = threadIdx.x;
    int i = blockIdx.x*256 + t;
    int d = (i < NSEG) ? deg[i] : 0;
    ps[t] = d; __syncthreads();
    for (int o=1;o<256;o<<=1) {
        int u = (t >= o) ? ps[t-o] : 0;
        __syncthreads();
        ps[t] += u;
        __syncthreads();
    }
    if (i < NSEG) {
        int off = part[blockIdx.x] + ps[t] - d;
        offs[i] = off; cursor[i] = off;
    }
    if (blockIdx.x == 0 && t == 0) offs[NSEG] = EE;
}

__global__ void place_k(const int* __restrict__ ei, const int* __restrict__ et,
                        int* __restrict__ cursor, unsigned short* __restrict__ csr)
{
    int e = blockIdx.x*blockDim.x + threadIdx.x;
    if (e >= EE) return;
    int r = et[e], dst = ei[EE + e], src = ei[e];
    int pos = atomicAdd(&cursor[dst*2 + r], 1);
    csr[pos] = (unsigned short)src;    // N=50000 < 65536
}

// ---------------- merged max-gather: one wave per (node,rel) segment ----------------
// also zeroes red[0..3] (block 0) for the following LN-reduce.
__global__ void gather2_k(const float* __restrict__ x, const int* __restrict__ offs,
                          const unsigned short* __restrict__ csr,
                          unsigned short* __restrict__ aggb, float* __restrict__ red)
{
    if (blockIdx.x == 0 && threadIdx.x < 4) red[threadIdx.x] = 0.f;
    int seg = (blockIdx.x*blockDim.x + threadIdx.x) >> 6;   // segment = node*2+r
    int lane = threadIdx.x & 63;
    if (seg >= NSEG) return;
    int node = seg >> 1, r = seg & 1;
    int beg = offs[seg], end = offs[seg+1];
    float2 m = make_float2(-3.402823466e+38f, -3.402823466e+38f);
    for (int j=beg;j<end;j++) {
        int src = csr[j];
        float2 v = *reinterpret_cast<const float2*>(x + (size_t)src*DD + lane*2);
        m.x = fmaxf(m.x, v.x);
        m.y = fmaxf(m.y, v.y);
    }
    if (beg == end) { m.x = 0.f; m.y = 0.f; }
    unsigned o = (unsigned)f2bf(m.x) | ((unsigned)f2bf(m.y) << 16);
    *reinterpret_cast<unsigned*>(aggb + (size_t)r*NN*DD + (size_t)node*DD + lane*2) = o;
}

// ---------------- graph layernorm apply ----------------
__global__ void norm_k(float* __restrict__ x, const float* __restrict__ g,
                       const float* __restrict__ b, const float* __restrict__ red)
{
    const float inv = 1.f / (float)(NN*DD);
    float mu  = red[0] * inv;
    float var = red[1] * inv - mu*mu;
    float rstd = rsqrtf(var + 1e-5f);
    int i = blockIdx.x*blockDim.x + threadIdx.x;   // exactly NN*DD threads
    int c = i & 127;
    x[i] = (x[i]-mu)*rstd*g[c] + b[c];
}

extern "C" void kernel_launch(void* const* d_in, const int* in_sizes, int n_in,
                              void* d_out, int out_size, void* d_ws, size_t ws_size,
                              hipStream_t stream)
{
    const float* desc  = (const float*)d_in[0];
    const float* tweet = (const float*)d_in[1];
    const float* numf  = (const float*)d_in[2];
    const float* catf  = (const float*)d_in[3];
    const int*   ei    = (const int*)d_in[4];
    const int*   et    = (const int*)d_in[5];
    const float* Wd=(const float*)d_in[6];  const float* bd=(const float*)d_in[7];
    const float* Wt=(const float*)d_in[8];  const float* bt=(const float*)d_in[9];
    const float* Wn=(const float*)d_in[10]; const float* bn=(const float*)d_in[11];
    const float* Wc=(const float*)d_in[12]; const float* bc=(const float*)d_in[13];
    const float* W1=(const float*)d_in[14]; const float* b1=(const float*)d_in[15];
    const float* rg1w=(const float*)d_in[16]; const float* rg1root=(const float*)d_in[17];
    const float* rg1b=(const float*)d_in[18];
    const float* ln1g=(const float*)d_in[19]; const float* ln1b=(const float*)d_in[20];
    const float* rg2w=(const float*)d_in[21]; const float* rg2root=(const float*)d_in[22];
    const float* rg2b=(const float*)d_in[23];
    const float* ln2g=(const float*)d_in[24]; const float* ln2b=(const float*)d_in[25];
    const float* W2=(const float*)d_in[26]; const float* b2=(const float*)d_in[27];
    const float* W3=(const float*)d_in[28]; const float* b3=(const float*)d_in[29];
    float* out = (float*)d_out;

    // workspace layout — IDENTICAL footprint to the known-good baseline (~79.2 MB)
    float* xa  = (float*)d_ws;                             // NN*DD f32
    float* xb  = xa + (size_t)NN*DD;                       // NN*DD f32
    unsigned short* aggb = (unsigned short*)(xb + (size_t)NN*DD);  // 2*NN*DD bf16
    unsigned short* aggb0 = aggb;
    unsigned short* aggb1 = aggb + (size_t)NN*DD;
    float* red = (float*)(aggb + (size_t)2*NN*DD);         // 4
    int*   deg    = (int*)(red + 4);                       // NSEG (400000 B)
    int*   offs   = deg + NSEG;                            // NSEG+1
    int*   cursor = offs + NSEG + 1;                       // NSEG
    int*   part   = cursor + NSEG;                         // NPART
    unsigned short* csr = (unsigned short*)(part + NPART); // EE u16

    // packed-weight images OVERLAY the deg array (dead after final_scan_k):
    // 98304 B + 262144 B = 360448 B <= NSEG*4 = 400000 B. 16-B aligned.
    unsigned short* bp768 = (unsigned short*)deg;
    unsigned short* bp128 = bp768 + 49152;

    dim3 blk(256);
    const int mblocks = (NN + 63) / 64;        // 782
    const int nelm_blocks = (NN*DD)/256;       // 25000
    const int edge_blocks = (EE+255)/256;      // 2344
    const int seg_blocks  = (NSEG*64)/256;     // 25000

    // 1-6. CSR build first (deg is scratch; freed for weight images afterwards)
    zero_int_k<<<(NSEG+255)/256, 256, 0, stream>>>(deg, NSEG);
    hist_k<<<edge_blocks, 256, 0, stream>>>(ei, et, deg);
    part_reduce_k<<<NPART, 256, 0, stream>>>(deg, part);
    part_scan_k<<<1, 512, 0, stream>>>(part);
    final_scan_k<<<NPART, 256, 0, stream>>>(deg, part, offs, cursor);   // last use of deg
    place_k<<<edge_blocks, 256, 0, stream>>>(ei, et, cursor, csr);

    // 7. pack weights to MFMA-fragment-ordered bf16 into deg-space (~5us)
    pack768_k<<<192, 256, 0, stream>>>(Wd, Wt, bp768);
    pack128_k<<<512, 256, 0, stream>>>(W1, rg1root, rg1w, rg1w + (size_t)DD*DD,
                                       rg2root, rg2w, rg2w + (size_t)DD*DD, W2, bp128);

    // 8. dual projection -> xa cols 0..63 ; 9. numcat -> cols 64..127
    proj_k<<<dim3(mblocks,2), blk, 0, stream>>>(desc, tweet, bp768, bd, bt, xa, NN);
    numcat_k<<<(NN*64)/256, 256, 0, stream>>>(numf, catf, Wn, bn, Wc, bc, xa);

    // 10. xb = leaky(xa@W1 + b1)   (packed slot 0)
    hipLaunchKernelGGL((mfgemm_k<1,0,1,0,0,0,0,0>), dim3(mblocks), blk, 0, stream,
                       xa, nullptr, nullptr, bp128, b1, xb, NN,
                       nullptr, nullptr, nullptr, nullptr);

    // 11-13. RGCN layer 1 (fused) + LN1   (slots 1=root, 2=w0, 3=w1)
    gather2_k<<<seg_blocks, 256, 0, stream>>>(xb, offs, csr, aggb, red);
    hipLaunchKernelGGL((mfgemm_k<3,6,0,0,1,1,2,3>), dim3(mblocks), blk, 0, stream,
                       xb, aggb0, aggb1, bp128, rg1b, xa, NN,
                       nullptr, nullptr, red, nullptr);
    norm_k<<<nelm_blocks, 256, 0, stream>>>(xa, ln1g, ln1b, red);

    // 14-16. RGCN layer 2 (fused) + LN2   (slots 4=root, 5=w0, 6=w1)
    gather2_k<<<seg_blocks, 256, 0, stream>>>(xa, offs, csr, aggb, red);
    hipLaunchKernelGGL((mfgemm_k<3,6,0,0,1,4,5,6>), dim3(mblocks), blk, 0, stream,
                       xa, aggb0, aggb1, bp128, rg2b, xb, NN,
                       nullptr, nullptr, red, nullptr);
    norm_k<<<nelm_blocks, 256, 0, stream>>>(xb, ln2g, ln2b, red);

    // 17. head fused into W2 GEMM epilogue: out = sigmoid(leaky(xb@W2+b2)@W3 + b3)
    //     (slot 7 = W2)
    hipLaunchKernelGGL((mfgemm_k<1,0,1,1,0,7,0,0>), dim3(mblocks), blk, 0, stream,
                       xb, nullptr, nullptr, bp128, b2, nullptr, NN,
                       W3, b3, nullptr, out);
}

// Round 7
// 755.893 us; speedup vs baseline: 1.0390x; 1.0390x over previous
//
#include <hip/hip_runtime.h>
#include <cstdint>
#include <cstddef>

#define NN 50000
#define EE 600000
#define DD 128
#define NSEG (NN*2)
#define NPART ((NSEG + 255) / 256)   // 391

typedef short bf16x8 __attribute__((ext_vector_type(8)));
typedef float f32x4 __attribute__((ext_vector_type(4)));

// async global->LDS DMA, 16B per lane; LDS dest is wave-uniform base + lane*16
#define GLDS16(gp, lp) __builtin_amdgcn_global_load_lds( \
    (const __attribute__((address_space(1))) void*)(gp), \
    (__attribute__((address_space(3))) void*)(lp), 16, 0, 0)

__device__ __forceinline__ float leaky_f(float x){ return x > 0.f ? x : 0.01f*x; }

__device__ __forceinline__ unsigned short f2bf(float f){
    unsigned u = __float_as_uint(f);
    u += 0x7fffu + ((u >> 16) & 1u);       // round-to-nearest-even
    return (unsigned short)(u >> 16);
}

// truncation hi/lo split: hi=trunc_bf16(a), lo=trunc_bf16(a-hi). err <= 2^-17 |a|
__device__ __forceinline__ void split8(const float* a, bf16x8& hi, bf16x8& lo){
#pragma unroll
    for (int j=0;j<8;j++){
        unsigned u  = __float_as_uint(a[j]);
        unsigned uh = u & 0xFFFF0000u;
        hi[j] = (short)(uh >> 16);
        float lf = a[j] - __uint_as_float(uh);
        lo[j] = (short)(__float_as_uint(lf) >> 16);
    }
}

// =============== weight pre-pack kernels ====================================
// Fragment order: for matrix, kb(768 only), ks, c, lane(=q*16+n16), j:
//   value = bf16( W[ k = kb*128 + ks*32 + q*8 + j ][ n = c*16 + n16 ] )
// so a wave's bf16x8 fragment load is a dense, lane-linear 1KB read.
// Packed images overlay the dead `deg` array (CSR scratch): footprint identical
// to the known-good baseline layout.

// Wd (768x32) -> images [6 kb][4 ks][2 c][64 lane][8 j]; Wt likewise. 24576 shorts each.
__global__ __launch_bounds__(256) void pack768_k(
    const float* __restrict__ Wd, const float* __restrict__ Wt,
    unsigned short* __restrict__ out)
{
    int idx = blockIdx.x*256 + threadIdx.x;       // 49152 total (= 192 blocks)
    int m = idx / 24576;
    int r = idx - m*24576;
    int kb   = r >> 12;
    int ks   = (r >> 10) & 3;
    int c    = (r >> 9) & 1;
    int lane = (r >> 3) & 63;
    int j    = r & 7;
    int q = lane >> 4, n16 = lane & 15;
    int k = kb*128 + ks*32 + q*8 + j;
    int n = c*16 + n16;
    const float* W = m ? Wt : Wd;
    out[idx] = f2bf(W[k*32 + n]);
}

// 8 matrices of 128x128 -> [4 ks][8 c][64 lane][8 j] = 16384 shorts per matrix.
__global__ __launch_bounds__(256) void pack128_k(
    const float* __restrict__ W0, const float* __restrict__ W1,
    const float* __restrict__ W2, const float* __restrict__ W3,
    const float* __restrict__ W4, const float* __restrict__ W5,
    const float* __restrict__ W6, const float* __restrict__ W7,
    unsigned short* __restrict__ out)
{
    int idx = blockIdx.x*256 + threadIdx.x;       // 131072 total (= 512 blocks)
    int m = idx >> 14;
    int r = idx & 16383;
    int ks   = r >> 12;
    int c    = (r >> 9) & 7;
    int lane = (r >> 3) & 63;
    int j    = r & 7;
    int q = lane >> 4, n16 = lane & 15;
    int k = ks*32 + q*8 + j;
    int n = c*16 + n16;
    const float* Ws[8] = {W0,W1,W2,W3,W4,W5,W6,W7};
    out[idx] = f2bf(Ws[m][k*128 + n]);
}

// ============ dual projection kernel: K=768, asm-pipelined A prefetch ========
// per block: 64 rows x 32 cols. B image (48KB) staged to LDS ONCE (one barrier);
// kb-loop's only VMEM = inline-asm volatile A-loads (compiler cannot sink them)
// with hand-counted s_waitcnt vmcnt(8) + sched_barrier(0) -> true depth-1 tile
// pipeline, 8KB/wave in flight. B via ds_read (lgkmcnt, disjoint counter).
__global__ __launch_bounds__(256) void proj_k(
    const float* __restrict__ A0, const float* __restrict__ A1,
    const unsigned short* __restrict__ Bp,
    const float* __restrict__ bias0, const float* __restrict__ bias1,
    float* __restrict__ C, int M)
{
    constexpr int K = 768, CT = 2;
    __shared__ unsigned short sB[24576];          // 48KB: this y's packed image, linear
    const int tid = threadIdx.x;
    const int lane = tid & 63;
    const int wv = tid >> 6;
    const int q = lane >> 4, n16 = lane & 15;
    const int bm = blockIdx.x * 64;
    const int arow = bm + wv*16 + n16;
    const float* A = blockIdx.y ? A1 : A0;
    const unsigned short* Bimg = Bp + (size_t)blockIdx.y * 24576;
    const float* bias = blockIdx.y ? bias1 : bias0;
    const int c0 = blockIdx.y * 32;
    const bool rowok = arow < M;
    const float* arowp = A + (size_t)(rowok ? arow : 0) * K;  // clamped; OOB outputs discarded

    // ---- stage B once: 48 wave-instrs of 1KB, linear copy (lane*16 implicit dest)
#pragma unroll
    for (int i=0;i<12;i++){
        GLDS16(Bimg + (size_t)(wv*12+i)*512 + lane*8,
               (unsigned char*)sB + (wv*12+i)*1024);
    }
    __syncthreads();   // drains staging; B resident for whole kernel

    f32x4 acc[CT];
#pragma unroll
    for (int c=0;c<CT;c++) acc[c] = (f32x4){0.f,0.f,0.f,0.f};

    f32x4 ar[2][8];    // A tile double buffer: produced ONLY by volatile asm loads

#define PROJ_ALOAD(BUF, KB) { \
    _Pragma("unroll") \
    for (int u=0;u<8;u++){ \
        const float* gp = arowp + (KB)*128 + (u>>1)*32 + q*8 + (u&1)*4; \
        asm volatile("global_load_dwordx4 %0, %1, off" : "=v"(ar[BUF][u]) : "v"(gp)); \
    } }

    PROJ_ALOAD(0, 0)
#pragma unroll
    for (int kb=0; kb<6; kb++){
        if (kb < 5) {
            PROJ_ALOAD((kb+1)&1, kb+1)                 // 8 newer loads in queue
            asm volatile("s_waitcnt vmcnt(8)");        // current tile's 8 complete
        } else {
            asm volatile("s_waitcnt vmcnt(0)");
        }
        __builtin_amdgcn_sched_barrier(0);             // rule #18: pin consumers after wait
#pragma unroll
        for (int ks=0; ks<4; ks++){
            f32x4 t0 = ar[kb&1][ks*2], t1 = ar[kb&1][ks*2+1];
            float a[8];
            a[0]=t0[0];a[1]=t0[1];a[2]=t0[2];a[3]=t0[3];
            a[4]=t1[0];a[5]=t1[1];a[6]=t1[2];a[7]=t1[3];
            bf16x8 ah, al; split8(a, ah, al);
#pragma unroll
            for (int c=0;c<CT;c++){
                bf16x8 b = *reinterpret_cast<const bf16x8*>(&sB[(size_t)(kb*8 + ks*2 + c)*512 + lane*8]);
                acc[c] = __builtin_amdgcn_mfma_f32_16x16x32_bf16(ah, b, acc[c], 0,0,0);
                acc[c] = __builtin_amdgcn_mfma_f32_16x16x32_bf16(al, b, acc[c], 0,0,0);
            }
        }
    }
#undef PROJ_ALOAD

    const int orow = bm + wv*16 + q*4;
#pragma unroll
    for (int c=0;c<CT;c++) {
        float bb = bias[c*16 + n16];
#pragma unroll
        for (int i=0;i<4;i++) {
            int r = orow + i;
            if (r < M) C[(size_t)r*DD + c0 + c*16 + n16] = leaky_f(acc[c][i] + bb);
        }
    }
}

// ============ K=128 MFMA GEMM, barrier-free, B from packed image (r5 ver) ===
// S stages: C = sum_s A_s @ B_s (+bias). BFMASK bit s => A_s is bf16 (else f32,
// split hi/lo). BI0..BI2 select packed-weight slots. LEAKY/HEAD/LNRED as before.
template<int S,int BFMASK,int LEAKY,int HEAD,int LNRED,int BI0,int BI1,int BI2>
__global__ __launch_bounds__(256) void mfgemm_k(
    const void* __restrict__ A0, const void* __restrict__ A1, const void* __restrict__ A2,
    const unsigned short* __restrict__ Bp,
    const float* __restrict__ bias, float* __restrict__ C, int M,
    const float* __restrict__ W3, const float* __restrict__ b3,
    float* __restrict__ red, float* __restrict__ outv)
{
    constexpr int CT = 8;
    const int tid = threadIdx.x;
    const int lane = tid & 63;
    const int wv = tid >> 6;
    const int q = lane >> 4, n16 = lane & 15;
    const int bm = blockIdx.x * 64;
    const int arow = bm + wv*16 + n16;
    const bool rowok = arow < M;

    f32x4 acc[CT];
#pragma unroll
    for (int c=0;c<CT;c++) acc[c] = (f32x4){0.f,0.f,0.f,0.f};

    const void* As[3] = {A0, A1, A2};
    constexpr int BI[3] = {BI0, BI1, BI2};
    const unsigned short* bpl = Bp + lane*8;

    float4 arf[2][2];     // f32-stage A double buffer
    bf16x8 arb[2];        // bf16-stage A double buffer

#define MG_LOADA(BUF, SS, KS) { \
    if (!((BFMASK >> (SS)) & 1)) { \
        if (rowok){ \
            const float* ap = (const float*)As[SS] + (size_t)arow*DD + (KS)*32 + q*8; \
            arf[BUF][0] = *reinterpret_cast<const float4*>(ap); \
            arf[BUF][1] = *reinterpret_cast<const float4*>(ap+4); \
        } else { \
            arf[BUF][0] = make_float4(0.f,0.f,0.f,0.f); \
            arf[BUF][1] = make_float4(0.f,0.f,0.f,0.f); \
        } \
    } else { \
        if (rowok){ \
            const unsigned short* ap = (const unsigned short*)As[SS] + (size_t)arow*DD + (KS)*32 + q*8; \
            arb[BUF] = *reinterpret_cast<const bf16x8*>(ap); \
        } else { \
            _Pragma("unroll") for (int jj=0;jj<8;jj++) arb[BUF][jj]=0; \
        } \
    } \
    __builtin_amdgcn_sched_barrier(0); }

#define MG_COMP(BUF, SS, KS) { \
    bf16x8 br[8]; \
    const unsigned short* bpp = bpl + BI[SS]*16384 + (KS)*4096; \
    _Pragma("unroll") \
    for (int c=0;c<8;c++) br[c] = *reinterpret_cast<const bf16x8*>(bpp + c*512); \
    if (!((BFMASK >> (SS)) & 1)) { \
        float a[8]; \
        float4 t0 = arf[BUF][0], t1 = arf[BUF][1]; \
        a[0]=t0.x;a[1]=t0.y;a[2]=t0.z;a[3]=t0.w; \
        a[4]=t1.x;a[5]=t1.y;a[6]=t1.z;a[7]=t1.w; \
        bf16x8 ah, al; split8(a, ah, al); \
        _Pragma("unroll") \
        for (int c=0;c<CT;c++){ \
            acc[c] = __builtin_amdgcn_mfma_f32_16x16x32_bf16(ah, br[c], acc[c], 0,0,0); \
            acc[c] = __builtin_amdgcn_mfma_f32_16x16x32_bf16(al, br[c], acc[c], 0,0,0); \
        } \
    } else { \
        _Pragma("unroll") \
        for (int c=0;c<CT;c++) \
            acc[c] = __builtin_amdgcn_mfma_f32_16x16x32_bf16(arb[BUF], br[c], acc[c], 0,0,0); \
    } }

    MG_LOADA(0, 0, 0)
#pragma unroll
    for (int t=0; t<S*4; t++){
        const int nt = t+1;
        if (nt < S*4) { MG_LOADA((nt&1), (nt>>2), (nt&3)) }
        MG_COMP((t&1), (t>>2), (t&3))
    }
#undef MG_LOADA
#undef MG_COMP

    // ---- epilogue
    const int orow = bm + wv*16 + q*4;
    if (HEAD) {
        float w3c[CT];
#pragma unroll
        for (int c=0;c<CT;c++) w3c[c] = W3[c*16 + n16];
        float bb3 = b3[0];
#pragma unroll
        for (int i=0;i<4;i++) {
            float t = 0.f;
#pragma unroll
            for (int c=0;c<CT;c++) {
                float v = acc[c][i] + bias[c*16 + n16];
                if (LEAKY) v = leaky_f(v);
                t = fmaf(v, w3c[c], t);
            }
#pragma unroll
            for (int m=1;m<16;m<<=1) t += __shfl_xor(t, m);
            int r = orow + i;
            if (n16 == 0 && r < M) outv[r] = 1.f / (1.f + expf(-(t + bb3)));
        }
    } else {
        float s = 0.f, ss = 0.f;
#pragma unroll
        for (int c=0;c<CT;c++) {
            float bb = bias[c*16 + n16];
#pragma unroll
            for (int i=0;i<4;i++) {
                int r = orow + i;
                if (r < M) {
                    float v = acc[c][i] + bb;
                    if (LEAKY) v = leaky_f(v);
                    C[(size_t)r*DD + c*16 + n16] = v;
                    if (LNRED) { s += v; ss = fmaf(v, v, ss); }
                }
            }
        }
        if (LNRED) {
#pragma unroll
            for (int o=32;o>0;o>>=1) { s += __shfl_down(s,o); ss += __shfl_down(ss,o); }
            __shared__ float rs[4], rss[4];
            if (lane == 0) { rs[wv] = s; rss[wv] = ss; }
            __syncthreads();
            if (tid == 0) {
                atomicAdd(&red[0], rs[0]+rs[1]+rs[2]+rs[3]);
                atomicAdd(&red[1], rss[0]+rss[1]+rss[2]+rss[3]);
            }
        }
    }
}

// ---------------- small-K projections (num: cols 64..95, cat: cols 96..127) --------
__global__ void numcat_k(const float* __restrict__ numf, const float* __restrict__ catf,
                         const float* __restrict__ Wn, const float* __restrict__ bn,
                         const float* __restrict__ Wc, const float* __restrict__ bc,
                         float* __restrict__ x)
{
    int t = blockIdx.x*blockDim.x + threadIdx.x;
    if (t >= NN*64) return;
    int n = t >> 6, c = t & 63;
    if (c < 32) {
        float acc = bn[c];
#pragma unroll
        for (int k=0;k<5;k++) acc = fmaf(numf[n*5+k], Wn[k*32+c], acc);
        x[(size_t)n*DD + 64 + c] = leaky_f(acc);
    } else {
        int cc = c - 32;
        float acc = bc[cc];
#pragma unroll
        for (int k=0;k<3;k++) acc = fmaf(catf[n*3+k], Wc[k*32+cc], acc);
        x[(size_t)n*DD + 96 + cc] = leaky_f(acc);
    }
}

// ---------------- CSR build ----------------
__global__ void zero_int_k(int* __restrict__ p, int n)
{
    int i = blockIdx.x*blockDim.x + threadIdx.x;
    if (i < n) p[i] = 0;
}

__global__ void hist_k(const int* __restrict__ ei, const int* __restrict__ et,
                       int* __restrict__ deg)
{
    int e = blockIdx.x*blockDim.x + threadIdx.x;
    if (e >= EE) return;
    atomicAdd(&deg[ei[EE + e]*2 + et[e]], 1);
}

__global__ __launch_bounds__(256) void part_reduce_k(const int* __restrict__ deg,
                                                     int* __restrict__ part)
{
    __shared__ int s[256];
    int t = threadIdx.x;
    int i = blockIdx.x*256 + t;
    s[t] = (i < NSEG) ? deg[i] : 0;
    __syncthreads();
#pragma unroll
    for (int o=128;o>0;o>>=1) {
        if (t < o) s[t] += s[t+o];
        __syncthreads();
    }
    if (t == 0) part[blockIdx.x] = s[0];
}

__global__ __launch_bounds__(512) void part_scan_k(int* __restrict__ part)
{
    __shared__ int ps[512];
    int t = threadIdx.x;
    int v = (t < NPART) ? part[t] : 0;
    ps[t] = v; __syncthreads();
    for (int o=1;o<512;o<<=1) {
        int u = (t >= o) ? ps[t-o] : 0;
        __syncthreads();
        ps[t] += u;
        __syncthreads();
    }
    if (t < NPART) part[t] = ps[t] - v;   // exclusive
}

__global__ __launch_bounds__(256) void final_scan_k(const int* __restrict__ deg,
                                                    const int* __restrict__ part,
                                                    int* __restrict__ offs,
                                                    int* __restrict__ cursor)
{
    __shared__ int ps[256];
    int t = threadIdx.x;
    int i = blockIdx.x*256 + t;
    int d = (i < NSEG) ? deg[i] : 0;
    ps[t] = d; __syncthreads();
    for (int o=1;o<256;o<<=1) {
        int u = (t >= o) ? ps[t-o] : 0;
        __syncthreads();
        ps[t] += u;
        __syncthreads();
    }
    if (i < NSEG) {
        int off = part[blockIdx.x] + ps[t] - d;
        offs[i] = off; cursor[i] = off;
    }
    if (blockIdx.x == 0 && t == 0) offs[NSEG] = EE;
}

__global__ void place_k(const int* __restrict__ ei, const int* __restrict__ et,
                        int* __restrict__ cursor, unsigned short* __restrict__ csr)
{
    int e = blockIdx.x*blockDim.x + threadIdx.x;
    if (e >= EE) return;
    int r = et[e], dst = ei[EE + e], src = ei[e];
    int pos = atomicAdd(&cursor[dst*2 + r], 1);
    csr[pos] = (unsigned short)src;    // N=50000 < 65536
}

// ---------------- merged max-gather: one wave per (node,rel) segment ----------------
// also zeroes red[0..3] (block 0) for the following LN-reduce.
__global__ void gather2_k(const float* __restrict__ x, const int* __restrict__ offs,
                          const unsigned short* __restrict__ csr,
                          unsigned short* __restrict__ aggb, float* __restrict__ red)
{
    if (blockIdx.x == 0 && threadIdx.x < 4) red[threadIdx.x] = 0.f;
    int seg = (blockIdx.x*blockDim.x + threadIdx.x) >> 6;   // segment = node*2+r
    int lane = threadIdx.x & 63;
    if (seg >= NSEG) return;
    int node = seg >> 1, r = seg & 1;
    int beg = offs[seg], end = offs[seg+1];
    float2 m = make_float2(-3.402823466e+38f, -3.402823466e+38f);
    for (int j=beg;j<end;j++) {
        int src = csr[j];
        float2 v = *reinterpret_cast<const float2*>(x + (size_t)src*DD + lane*2);
        m.x = fmaxf(m.x, v.x);
        m.y = fmaxf(m.y, v.y);
    }
    if (beg == end) { m.x = 0.f; m.y = 0.f; }
    unsigned o = (unsigned)f2bf(m.x) | ((unsigned)f2bf(m.y) << 16);
    *reinterpret_cast<unsigned*>(aggb + (size_t)r*NN*DD + (size_t)node*DD + lane*2) = o;
}

// ---------------- graph layernorm apply ----------------
__global__ void norm_k(float* __restrict__ x, const float* __restrict__ g,
                       const float* __restrict__ b, const float* __restrict__ red)
{
    const float inv = 1.f / (float)(NN*DD);
    float mu  = red[0] * inv;
    float var = red[1] * inv - mu*mu;
    float rstd = rsqrtf(var + 1e-5f);
    int i = blockIdx.x*blockDim.x + threadIdx.x;   // exactly NN*DD threads
    int c = i & 127;
    x[i] = (x[i]-mu)*rstd*g[c] + b[c];
}

extern "C" void kernel_launch(void* const* d_in, const int* in_sizes, int n_in,
                              void* d_out, int out_size, void* d_ws, size_t ws_size,
                              hipStream_t stream)
{
    const float* desc  = (const float*)d_in[0];
    const float* tweet = (const float*)d_in[1];
    const float* numf  = (const float*)d_in[2];
    const float* catf  = (const float*)d_in[3];
    const int*   ei    = (const int*)d_in[4];
    const int*   et    = (const int*)d_in[5];
    const float* Wd=(const float*)d_in[6];  const float* bd=(const float*)d_in[7];
    const float* Wt=(const float*)d_in[8];  const float* bt=(const float*)d_in[9];
    const float* Wn=(const float*)d_in[10]; const float* bn=(const float*)d_in[11];
    const float* Wc=(const float*)d_in[12]; const float* bc=(const float*)d_in[13];
    const float* W1=(const float*)d_in[14]; const float* b1=(const float*)d_in[15];
    const float* rg1w=(const float*)d_in[16]; const float* rg1root=(const float*)d_in[17];
    const float* rg1b=(const float*)d_in[18];
    const float* ln1g=(const float*)d_in[19]; const float* ln1b=(const float*)d_in[20];
    const float* rg2w=(const float*)d_in[21]; const float* rg2root=(const float*)d_in[22];
    const float* rg2b=(const float*)d_in[23];
    const float* ln2g=(const float*)d_in[24]; const float* ln2b=(const float*)d_in[25];
    const float* W2=(const float*)d_in[26]; const float* b2=(const float*)d_in[27];
    const float* W3=(const float*)d_in[28]; const float* b3=(const float*)d_in[29];
    float* out = (float*)d_out;

    // workspace layout — IDENTICAL footprint to the known-good baseline (~79.2 MB)
    float* xa  = (float*)d_ws;                             // NN*DD f32
    float* xb  = xa + (size_t)NN*DD;                       // NN*DD f32
    unsigned short* aggb = (unsigned short*)(xb + (size_t)NN*DD);  // 2*NN*DD bf16
    unsigned short* aggb0 = aggb;
    unsigned short* aggb1 = aggb + (size_t)NN*DD;
    float* red = (float*)(aggb + (size_t)2*NN*DD);         // 4
    int*   deg    = (int*)(red + 4);                       // NSEG (400000 B)
    int*   offs   = deg + NSEG;                            // NSEG+1
    int*   cursor = offs + NSEG + 1;                       // NSEG
    int*   part   = cursor + NSEG;                         // NPART
    unsigned short* csr = (unsigned short*)(part + NPART); // EE u16

    // packed-weight images OVERLAY the deg array (dead after final_scan_k):
    // 98304 B + 262144 B = 360448 B <= NSEG*4 = 400000 B. 16-B aligned.
    unsigned short* bp768 = (unsigned short*)deg;
    unsigned short* bp128 = bp768 + 49152;

    dim3 blk(256);
    const int mblocks = (NN + 63) / 64;        // 782
    const int nelm_blocks = (NN*DD)/256;       // 25000
    const int edge_blocks = (EE+255)/256;      // 2344
    const int seg_blocks  = (NSEG*64)/256;     // 25000

    // 1-6. CSR build first (deg is scratch; freed for weight images afterwards)
    zero_int_k<<<(NSEG+255)/256, 256, 0, stream>>>(deg, NSEG);
    hist_k<<<edge_blocks, 256, 0, stream>>>(ei, et, deg);
    part_reduce_k<<<NPART, 256, 0, stream>>>(deg, part);
    part_scan_k<<<1, 512, 0, stream>>>(part);
    final_scan_k<<<NPART, 256, 0, stream>>>(deg, part, offs, cursor);   // last use of deg
    place_k<<<edge_blocks, 256, 0, stream>>>(ei, et, cursor, csr);

    // 7. pack weights to MFMA-fragment-ordered bf16 into deg-space (~5us)
    pack768_k<<<192, 256, 0, stream>>>(Wd, Wt, bp768);
    pack128_k<<<512, 256, 0, stream>>>(W1, rg1root, rg1w, rg1w + (size_t)DD*DD,
                                       rg2root, rg2w, rg2w + (size_t)DD*DD, W2, bp128);

    // 8. dual projection -> xa cols 0..63 ; 9. numcat -> cols 64..127
    proj_k<<<dim3(mblocks,2), blk, 0, stream>>>(desc, tweet, bp768, bd, bt, xa, NN);
    numcat_k<<<(NN*64)/256, 256, 0, stream>>>(numf, catf, Wn, bn, Wc, bc, xa);

    // 10. xb = leaky(xa@W1 + b1)   (packed slot 0)
    hipLaunchKernelGGL((mfgemm_k<1,0,1,0,0,0,0,0>), dim3(mblocks), blk, 0, stream,
                       xa, nullptr, nullptr, bp128, b1, xb, NN,
                       nullptr, nullptr, nullptr, nullptr);

    // 11-13. RGCN layer 1 (fused) + LN1   (slots 1=root, 2=w0, 3=w1)
    gather2_k<<<seg_blocks, 256, 0, stream>>>(xb, offs, csr, aggb, red);
    hipLaunchKernelGGL((mfgemm_k<3,6,0,0,1,1,2,3>), dim3(mblocks), blk, 0, stream,
                       xb, aggb0, aggb1, bp128, rg1b, xa, NN,
                       nullptr, nullptr, red, nullptr);
    norm_k<<<nelm_blocks, 256, 0, stream>>>(xa, ln1g, ln1b, red);

    // 14-16. RGCN layer 2 (fused) + LN2   (slots 4=root, 5=w0, 6=w1)
    gather2_k<<<seg_blocks, 256, 0, stream>>>(xa, offs, csr, aggb, red);
    hipLaunchKernelGGL((mfgemm_k<3,6,0,0,1,4,5,6>), dim3(mblocks), blk, 0, stream,
                       xa, aggb0, aggb1, bp128, rg2b, xb, NN,
                       nullptr, nullptr, red, nullptr);
    norm_k<<<nelm_blocks, 256, 0, stream>>>(xb, ln2g, ln2b, red);

    // 17. head fused into W2 GEMM epilogue: out = sigmoid(leaky(xb@W2+b2)@W3 + b3)
    //     (slot 7 = W2)
    hipLaunchKernelGGL((mfgemm_k<1,0,1,1,0,7,0,0>), dim3(mblocks), blk, 0, stream,
                       xb, nullptr, nullptr, bp128, b2, nullptr, NN,
                       W3, b3, nullptr, out);
}